// Round 15
// baseline (206.235 us; speedup 1.0000x reference)
//
#include <hip/hip_runtime.h>
#include <cstdint>

#define B_    128
#define T_    2048
#define NIN_  16
#define NH_   128
#define NOUT_ 5

#define ALPHA_I_ 0.75f
#define ALPHA_V_ 0.96875f
#define THETA_   64.0f

#define NCHUNK_ 8
#define CHT_    256     // fused-layer chunk (R8/R11 swept 512/128: both worse)
#define WARM_   96      // warmup timesteps (3 sub-chunks of 32)
// tail scan chunking (R15: 16 x 128 -> 160 blocks, 224 serial steps/thread)
#define NCHUNK3_ 16
#define CHT3_    128

typedef short bf16x8 __attribute__((ext_vector_type(8)));
typedef float f32x16 __attribute__((ext_vector_type(16)));
typedef int   i32x2  __attribute__((ext_vector_type(2)));

__device__ __forceinline__ float mulrn(float a, float b) { return __fmul_rn(a, b); }
__device__ __forceinline__ float addrn(float a, float b) { return __fadd_rn(a, b); }

__device__ __forceinline__ uint16_t f2bf(float x) {  // RNE f32->bf16
  uint32_t u = __float_as_uint(x);
  return (uint16_t)((u + 0x7FFFu + ((u >> 16) & 1u)) >> 16);
}

// R9: pure-VALU bit->bf16 expand. Word j carries bits 2j (lo half) and
// 2j+1 (hi half) as bf16 1.0/0.0 — zero LDS traffic in the loop.
__device__ __forceinline__ bf16x8 expand8v(uint32_t byt) {
  union { uint32_t w[4]; bf16x8 f; } r;
#pragma unroll
  for (int j = 0; j < 4; j++) {
    uint32_t b0 = (byt >> (2 * j)) & 1u;
    uint32_t b1 = (byt >> (2 * j + 1)) & 1u;
    r.w[j] = (b0 ? 0x3F80u : 0u) | (b1 ? 0x3F800000u : 0u);
  }
  return r.f;
}

// ---------------------------------------------------------------------------
// R8 merged prep+pack (one launch, 257 blocks x 1024 threads):
// blocks 0..255: pack (16 gw-groups per block); block 256: prep (R5-proven).
// ---------------------------------------------------------------------------
__global__ __launch_bounds__(1024) void prep_pack_kernel(
    const float* __restrict__ spike, uint16_t* __restrict__ Xb,
    const float* __restrict__ fc1_v, const float* __restrict__ fc1_g,
    const float* __restrict__ fc2_v, const float* __restrict__ fc2_g,
    const float* __restrict__ fc3_v, const float* __restrict__ fc3_g,
    const float* __restrict__ delay1, const float* __restrict__ delay2,
    uint16_t* __restrict__ w1swz, uint16_t* __restrict__ wswz,
    float* __restrict__ w3T, float4* __restrict__ efo1, float4* __restrict__ efo2,
    float* __restrict__ counts) {
  int tid = threadIdx.x;
  if (blockIdx.x < 256) {
    // ---- pack ----
    int gw = blockIdx.x * 16 + (tid >> 6);
    int lane = tid & 63;
    int b = gw >> 5;
    int t = (gw & 31) * 64 + lane;
    const float* sp = spike + (size_t)b * NIN_ * T_ + t;
    uint32_t mask = 0;
#pragma unroll
    for (int c = 0; c < NIN_; c++) {
      unsigned long long bal = __ballot(sp[(size_t)c * T_] != 0.f);
      mask |= (uint32_t)((bal >> lane) & 1ull) << c;
    }
    Xb[(size_t)b * T_ + t] = (uint16_t)mask;
    return;
  }
  // ---- prep (R5-proven body) ----
  __shared__ float s_n1[NH_], s_n2[NH_], s_n3[8], s_g2[NH_];
  {
    int o = tid >> 3, sub = tid & 7;  // 1024 threads -> 128 rows x 8 lanes
    float ss = 0.f;
    for (int c = sub; c < NIN_; c += 8) { float v = fc1_v[o * NIN_ + c]; ss = __fmaf_rn(v, v, ss); }
    ss += __shfl_down(ss, 4, 64); ss += __shfl_down(ss, 2, 64); ss += __shfl_down(ss, 1, 64);
    if (sub == 0) s_n1[o] = sqrtf(ss);
    float ss2 = 0.f;
    for (int c = sub; c < NH_; c += 8) { float v = fc2_v[o * NH_ + c]; ss2 = __fmaf_rn(v, v, ss2); }
    ss2 += __shfl_down(ss2, 4, 64); ss2 += __shfl_down(ss2, 2, 64); ss2 += __shfl_down(ss2, 1, 64);
    if (sub == 0) s_n2[o] = sqrtf(ss2);
  }
  if (tid < NOUT_ * 8) {
    int o = tid >> 3, sub = tid & 7;
    float ss = 0.f;
    for (int c = sub; c < NH_; c += 8) { float v = fc3_v[o * NH_ + c]; ss = __fmaf_rn(v, v, ss); }
    ss += __shfl_down(ss, 4, 64); ss += __shfl_down(ss, 2, 64); ss += __shfl_down(ss, 1, 64);
    if (sub == 0) s_n3[o] = sqrtf(ss);
  }
  if (tid < NH_) s_g2[tid] = fc2_g[tid];
  if (tid < 3) counts[tid] = 0.f;
  __syncthreads();

  if (tid < NH_) {
    float d1 = delay1[tid];
    float fl = floorf(d1);
    float f = __fsub_rn(d1, fl);
    efo1[tid] = make_float4(__int_as_float((int)fl + 1), f, __fsub_rn(1.0f, f), 0.f);
    float d2 = delay2[tid];
    float fl2 = floorf(d2);
    float f2v = __fsub_rn(d2, fl2);
    efo2[tid] = make_float4(__int_as_float((int)fl2 + 1), f2v, __fsub_rn(1.0f, f2v), 0.f);
    w3T[tid * 8 + 5] = f2v;
    w3T[tid * 8 + 6] = __fsub_rn(1.0f, f2v);
    w3T[tid * 8 + 7] = 0.f;
  }
  for (int i = tid; i < NH_ * NIN_; i += 1024) {
    int o = i >> 4, c = i & 15;
    float wv = 64.0f * __fdiv_rn(mulrn(fc1_g[o], fc1_v[i]), s_n1[o]);
    int mt = o >> 5, lane = (o & 31) + 32 * ((c >> 3) & 1), j = c & 7;
    w1swz[(mt * 64 + lane) * 8 + j] = f2bf(wv);
  }
  for (int i = tid; i < NH_ * NH_; i += 1024) {
    int o = i >> 7, c = i & 127;
    float wv = 64.0f * __fdiv_rn(mulrn(s_g2[o], fc2_v[i]), s_n2[o]);
    float d1 = delay1[c];
    float f = __fsub_rn(d1, floorf(d1));
    int lane = (o & 31) + 32 * ((c >> 3) & 1);
    int ks = c >> 4, j = c & 7, mt = o >> 5;
    wswz[((size_t)((0 * 4 + mt) * 8 + ks) * 64 + lane) * 8 + j] = f2bf(__fmul_rn(wv, f));
    wswz[((size_t)((1 * 4 + mt) * 8 + ks) * 64 + lane) * 8 + j] =
        f2bf(__fmul_rn(wv, __fsub_rn(1.0f, f)));
  }
  for (int i = tid; i < NOUT_ * NH_; i += 1024) {
    int o = i / NH_, c = i & 127;
    float wv = 64.0f * __fdiv_rn(mulrn(fc3_g[o], fc3_v[i]), s_n3[o]);
    w3T[c * 8 + o] = wv;
  }
}

// ---------------------------------------------------------------------------
// R13 interleaved gather+scan: {4 permlane -> 8 scan steps} x4 keeps only
// ev[4]+od[4] live; aA/aB die progressively. Bit-exact vs R10.
// ---------------------------------------------------------------------------
#define GATHER_AND_SCAN(aA, aB, hi, u, v, m)                               \
  {                                                                        \
    m = 0u;                                                                \
    _Pragma("unroll") for (int k = 0; k < 4; k++) {                        \
      float ev[4], od[4];                                                  \
      _Pragma("unroll") for (int i = 0; i < 4; i++) {                      \
        i32x2 pr_ = __builtin_amdgcn_permlane32_swap(                      \
            __float_as_int(aA[4 * k + i]), __float_as_int(aB[4 * k + i]),  \
            false, false);                                                 \
        ev[i] = __int_as_float(pr_[0]);                                    \
        od[i] = __int_as_float(pr_[1]);                                    \
      }                                                                    \
      _Pragma("unroll") for (int tt = 0; tt < 8; tt++) {                   \
        float z = (tt < 4) ? ev[tt & 3] : od[tt & 3];                      \
        u = addrn(mulrn(ALPHA_I_, u), z);                                  \
        v = addrn(mulrn(ALPHA_V_, v), u);                                  \
        bool sbit = (v >= THETA_);                                         \
        v = sbit ? 0.f : v;                                                \
        m |= sbit ? (1u << (8 * k + tt)) : 0u;                             \
      }                                                                    \
    }                                                                      \
  }

// ---------------------------------------------------------------------------
// R5 fused delay-shift + bit-transpose epilogue; R10 sign-bit ballot pred.
// ---------------------------------------------------------------------------
#define EMIT_PT(m, m_prev, e_o, ptw, chwstart)                             \
  {                                                                        \
    uint32_t sm = (uint32_t)((((uint64_t)(m) << 32) | (m_prev)) >> (32 - (e_o))); \
    uint32_t myword = 0u;                                                  \
    _Pragma("unroll") for (int j = 0; j < 32; j++) {                       \
      unsigned long long bal_ = __ballot((int)(sm << (31 - j)) < 0);       \
      uint32_t w_ = hi ? (uint32_t)(bal_ >> 32) : (uint32_t)bal_;          \
      myword = (tl == j) ? w_ : myword;                                    \
    }                                                                      \
    ptw[(size_t)(1 + (chwstart) + tl) * 4 + (pair * 2 + hi)] = myword;     \
  }

// ---------------------------------------------------------------------------
// Fused layer 1 (R13-proven): wave = 2 o-tiles, 2 MFMA (loop-invariant zero
// C), interleaved permlane gather + in-register scan, delay-shift+ballot-
// transpose to PT1. grid (NCHUNK_, B), block 128.
// ---------------------------------------------------------------------------
__global__ __launch_bounds__(128, 2) void fused_layer1(const uint16_t* __restrict__ Xb,
                                                       const uint16_t* __restrict__ w1swz,
                                                       const float4* __restrict__ efo,
                                                       uint32_t* __restrict__ PT1,
                                                       float* __restrict__ cnt) {
  int tid = threadIdx.x;
  int pair = tid >> 6, lane = tid & 63;
  int hi = lane >> 5, tl = lane & 31;
  int ci = blockIdx.x, b = blockIdx.y;
  const bf16x8* w1v = (const bf16x8*)w1swz;
  bf16x8 wA = w1v[(pair * 2 + 0) * 64 + lane];
  bf16x8 wB = w1v[(pair * 2 + 1) * 64 + lane];
  int e_o = __float_as_int(efo[tid].x);   // channel o = tid; e in [1,11]

  int wch = (ci == 0) ? 0 : (WARM_ / 32);
  int nch = CHT_ / 32 + wch;
  int chbase0 = ci * CHT_ - wch * 32;
  const uint16_t* xb = Xb + (size_t)b * T_;
  uint32_t* ptw = PT1 + (size_t)b * (T_ + 1) * 4;

  f32x16 zacc;
#pragma unroll
  for (int r = 0; r < 16; r++) zacc[r] = 0.f;

  float u = 0.f, v = 0.f, csum = 0.f;
  uint32_t m_prev = 0u;
  uint32_t x = xb[chbase0 + tl];
  for (int g = 0; g < nch; g++) {
    uint32_t xn = (g + 1 < nch) ? (uint32_t)xb[chbase0 + (g + 1) * 32 + tl] : 0u;
    uint32_t byt = (x >> (8 * hi)) & 0xFFu;
    bf16x8 e = expand8v(byt);
    f32x16 aA, aB;
    aA = __builtin_amdgcn_mfma_f32_32x32x16_bf16(e, wA, zacc, 0, 0, 0);
    aB = __builtin_amdgcn_mfma_f32_32x32x16_bf16(e, wB, zacc, 0, 0, 0);
    uint32_t m;
    GATHER_AND_SCAN(aA, aB, hi, u, v, m);
    if (g >= wch) {
      int chwstart = chbase0 + g * 32;
      EMIT_PT(m, m_prev, e_o, ptw, chwstart);
      int gw = chwstart >> 5;
      int pc = __popc(m);
      if (gw == 63) pc -= (int)(m >> 31);
      csum += (float)pc;
    }
    m_prev = m;
    x = xn;
  }
  if (ci == 0 && tid < 4) ptw[tid] = 0u;   // PT row 0 = zero guard
  for (int off = 32; off; off >>= 1) csum += __shfl_down(csum, off, 64);
  if (lane == 0) atomicAdd(cnt, csum);
}

// ---------------------------------------------------------------------------
// Fused layer 2 (R13-proven): wave = 2 o-tiles, baked f/(1-f) weight
// fragments in registers, 2 delay taps from PT1 rows, 4 MFMA/ks,
// interleaved permlane gather + scan, delay2-shift+transpose to PT2.
// grid (NCHUNK_, B), block 128.
// ---------------------------------------------------------------------------
__global__ __launch_bounds__(128, 2) void fused_layer2(const uint32_t* __restrict__ PT1,
                                                       const uint16_t* __restrict__ wswz,
                                                       const float4* __restrict__ efo,
                                                       uint32_t* __restrict__ PT2,
                                                       float* __restrict__ cnt) {
  int tid = threadIdx.x;
  int pair = tid >> 6, lane = tid & 63;
  int hi = lane >> 5, tl = lane & 31;
  int ci = blockIdx.x, b = blockIdx.y;
  const bf16x8* wsv = (const bf16x8*)wswz;
  int mtA = pair * 2, mtB = pair * 2 + 1;
  bf16x8 wfA[8], woA[8], wfB[8], woB[8];
#pragma unroll
  for (int ks = 0; ks < 8; ks++) {
    wfA[ks] = wsv[((size_t)((0 * 4 + mtA) * 8 + ks) * 64) + lane];
    woA[ks] = wsv[((size_t)((1 * 4 + mtA) * 8 + ks) * 64) + lane];
    wfB[ks] = wsv[((size_t)((0 * 4 + mtB) * 8 + ks) * 64) + lane];
    woB[ks] = wsv[((size_t)((1 * 4 + mtB) * 8 + ks) * 64) + lane];
  }
  int e_o = __float_as_int(efo[tid].x);   // channel o = tid; e in [1,11]

  int wch = (ci == 0) ? 0 : (WARM_ / 32);
  int nch = CHT_ / 32 + wch;
  int chbase0 = ci * CHT_ - wch * 32;
  const uint4* pt = (const uint4*)PT1 + (size_t)b * (T_ + 1);
  uint32_t* ptw = PT2 + (size_t)b * (T_ + 1) * 4;

  float u = 0.f, v = 0.f, csum = 0.f;
  uint32_t m_prev = 0u;
  uint4 R0 = pt[chbase0 + tl];
  uint4 R1 = pt[chbase0 + tl + 1];
  for (int g = 0; g < nch; g++) {
    uint4 R0n = R0, R1n = R1;
    if (g + 1 < nch) {
      R0n = pt[chbase0 + (g + 1) * 32 + tl];
      R1n = pt[chbase0 + (g + 1) * 32 + tl + 1];
    }
    uint32_t r0w[4] = {R0.x, R0.y, R0.z, R0.w};
    uint32_t r1w[4] = {R1.x, R1.y, R1.z, R1.w};
    f32x16 aA, aB;
#pragma unroll
    for (int r = 0; r < 16; r++) { aA[r] = 0.f; aB[r] = 0.f; }
#pragma unroll
    for (int ks = 0; ks < 8; ks++) {
      int sh = 16 * (ks & 1) + 8 * hi;
      uint32_t b0 = (r0w[ks >> 1] >> sh) & 0xFFu;  // tap s[t-e-1] -> Wf
      uint32_t b1 = (r1w[ks >> 1] >> sh) & 0xFFu;  // tap s[t-e]   -> Wof
      bf16x8 e0 = expand8v(b0);
      bf16x8 e1 = expand8v(b1);
      aA = __builtin_amdgcn_mfma_f32_32x32x16_bf16(e0, wfA[ks], aA, 0, 0, 0);
      aA = __builtin_amdgcn_mfma_f32_32x32x16_bf16(e1, woA[ks], aA, 0, 0, 0);
      aB = __builtin_amdgcn_mfma_f32_32x32x16_bf16(e0, wfB[ks], aB, 0, 0, 0);
      aB = __builtin_amdgcn_mfma_f32_32x32x16_bf16(e1, woB[ks], aB, 0, 0, 0);
    }
    uint32_t m;
    GATHER_AND_SCAN(aA, aB, hi, u, v, m);
    if (g >= wch) {
      int chwstart = chbase0 + g * 32;
      EMIT_PT(m, m_prev, e_o, ptw, chwstart);
      int gw = chwstart >> 5;
      int pc = __popc(m);
      if (gw == 63) pc -= (int)(m >> 31);
      csum += (float)pc;
    }
    m_prev = m;
    R0 = R0n; R1 = R1n;
  }
  if (ci == 0 && tid < 4) ptw[tid] = 0u;   // PT row 0 = zero guard
  for (int off = 32; off; off >>= 1) csum += __shfl_down(csum, off, 64);
  if (lane == 0) atomicAdd(cnt, csum);
}

// ---------------------------------------------------------------------------
// gemm3 (vector, R5-proven): 5 outputs from pre-shifted PT2 rows.
// ---------------------------------------------------------------------------
__global__ __launch_bounds__(256) void gemm3_kernel(const uint32_t* __restrict__ PTpad,
                                                    const float* __restrict__ w3T,
                                                    float* __restrict__ z) {
  int tid = threadIdx.x;
  int t = blockIdx.x * 256 + tid;
  int b = blockIdx.y;
  const uint4* pt = (const uint4*)PTpad + (size_t)b * (T_ + 1);
  uint4 R0 = pt[t];
  uint4 R1 = pt[t + 1];
  uint32_t r0w[4] = {R0.x, R0.y, R0.z, R0.w};
  uint32_t r1w[4] = {R1.x, R1.y, R1.z, R1.w};

  float acc[NOUT_];
#pragma unroll
  for (int o = 0; o < NOUT_; o++) acc[o] = 0.f;

#pragma unroll
  for (int c = 0; c < NH_; c++) {
    const float* wc = w3T + (c << 3);
    float f = wc[5], omf = wc[6];
    float fb0 = (float)((r0w[c >> 5] >> (c & 31)) & 1u);
    float fb1 = (float)((r1w[c >> 5] >> (c & 31)) & 1u);
    float val = __fmaf_rn(omf, fb1, __fmul_rn(f, fb0));
#pragma unroll
    for (int o = 0; o < NOUT_; o++) acc[o] = __fmaf_rn(wc[o], val, acc[o]);
  }

#pragma unroll
  for (int o = 0; o < NOUT_; o++)
    z[((size_t)b * NOUT_ + o) * T_ + t] = acc[o];
}

// ---------------------------------------------------------------------------
// Chunked layer-3 scan (R15: 16 chunks x 128 t, block 64, grid 160 — 2x CU
// coverage vs R14 and 224 serial steps/thread vs 352; update order per
// (row,chunk) byte-identical; count exact integer sum, order-independent;
// t=T-1 exclusion falls in chunk 15 group 7 k=15).
// ---------------------------------------------------------------------------
__global__ __launch_bounds__(64) void scan3_kernel(const float* __restrict__ z3,
                                                   float* __restrict__ out,
                                                   float* __restrict__ cnt) {
  int id = blockIdx.x * 64 + threadIdx.x;
  int row = id % (B_ * NOUT_);
  int ci = id / (B_ * NOUT_);
  int tstart = ci * CHT3_;
  int t0 = (ci == 0) ? 0 : tstart - WARM_;
  const float4* zp4 = (const float4*)(z3 + (size_t)row * T_);

  float u = 0.f, v = 0.f, carry = 0.f;
  int cnt_i = 0;
  for (int gg = t0 / 16; gg < tstart / 16; gg++) {
#pragma unroll
    for (int q = 0; q < 4; q++) {
      float4 cv = zp4[gg * 4 + q];
      float zv[4] = {cv.x, cv.y, cv.z, cv.w};
#pragma unroll
      for (int j = 0; j < 4; j++) {
        u = addrn(mulrn(ALPHA_I_, u), zv[j]);
        v = addrn(mulrn(ALPHA_V_, v), u);
        bool s = (v >= THETA_);
        v = s ? 0.f : v;
        carry = s ? 1.f : 0.f;
      }
    }
  }
  float4* op4 = (float4*)(out + (size_t)row * T_ + tstart);
  for (int gg = 0; gg < CHT3_ / 16; gg++) {
    float sarr[16];
#pragma unroll
    for (int q = 0; q < 4; q++) {
      float4 cv = zp4[(tstart / 16 + gg) * 4 + q];
      float zv[4] = {cv.x, cv.y, cv.z, cv.w};
#pragma unroll
      for (int j = 0; j < 4; j++) {
        u = addrn(mulrn(ALPHA_I_, u), zv[j]);
        v = addrn(mulrn(ALPHA_V_, v), u);
        bool s = (v >= THETA_);
        v = s ? 0.f : v;
        sarr[q * 4 + j] = s ? 1.f : 0.f;
      }
    }
#pragma unroll
    for (int k = 0; k < 16; k++) {
      int t = tstart + gg * 16 + k;
      if (t < T_ - 1) cnt_i += (sarr[k] != 0.f) ? 1 : 0;
    }
    op4[gg * 4 + 0] = make_float4(carry, sarr[0], sarr[1], sarr[2]);
    op4[gg * 4 + 1] = make_float4(sarr[3], sarr[4], sarr[5], sarr[6]);
    op4[gg * 4 + 2] = make_float4(sarr[7], sarr[8], sarr[9], sarr[10]);
    op4[gg * 4 + 3] = make_float4(sarr[11], sarr[12], sarr[13], sarr[14]);
    carry = sarr[15];
  }
  float c = (float)cnt_i;
  for (int off = 32; off; off >>= 1) c += __shfl_down(c, off, 64);
  if ((threadIdx.x & 63) == 0) atomicAdd(cnt, c);
}

// ---------------------------------------------------------------------------
extern "C" void kernel_launch(void* const* d_in, const int* in_sizes, int n_in,
                              void* d_out, int out_size, void* d_ws, size_t ws_size,
                              hipStream_t stream) {
  (void)in_sizes; (void)n_in; (void)out_size; (void)ws_size;
  const float* spike  = (const float*)d_in[0];
  const float* fc1_v  = (const float*)d_in[1];
  const float* fc1_g  = (const float*)d_in[2];
  const float* fc2_v  = (const float*)d_in[3];
  const float* fc2_g  = (const float*)d_in[4];
  const float* fc3_v  = (const float*)d_in[5];
  const float* fc3_g  = (const float*)d_in[6];
  const float* delay1 = (const float*)d_in[7];
  const float* delay2 = (const float*)d_in[8];
  float* out = (float*)d_out;

  float* ws = (float*)d_ws;
  float* w3T       = ws;                         // 1024 f
  float4* efo1     = (float4*)(ws + 1024);       // 512 f
  float4* efo2     = (float4*)(ws + 1536);       // 512 f
  uint16_t* w1swz  = (uint16_t*)(ws + 2048);     // 2048 u16 = 1024 f
  uint16_t* wswz   = (uint16_t*)(ws + 3072);     // 32768 u16 = 16384 f
  uint16_t* Xb     = (uint16_t*)(ws + 19456);    // B*T u16 = 131072 f
  uint32_t* PT1    = (uint32_t*)(ws + 150528);   // B*(T+1)*4 u32 (layer1 out)
  uint32_t* PT2    = (uint32_t*)(ws + 1264640);  // B*(T+1)*4 u32 (layer2 out)
  float* z3        = ws + 2313728;               // B*5*T f32
  float* counts = out + (size_t)B_ * NOUT_ * T_;

  prep_pack_kernel<<<dim3(257), 1024, 0, stream>>>(
      spike, Xb, fc1_v, fc1_g, fc2_v, fc2_g, fc3_v, fc3_g,
      delay1, delay2, w1swz, wswz, w3T, efo1, efo2, counts);

  fused_layer1<<<dim3(NCHUNK_, B_), 128, 0, stream>>>(Xb, w1swz, efo1, PT1, counts + 0);

  fused_layer2<<<dim3(NCHUNK_, B_), 128, 0, stream>>>(PT1, wswz, efo2, PT2, counts + 1);

  gemm3_kernel<<<dim3(T_ / 256, B_), 256, 0, stream>>>(PT2, w3T, z3);
  scan3_kernel<<<dim3(NCHUNK3_ * B_ * NOUT_ / 64), 64, 0, stream>>>(z3, out, counts + 2);
}

// Round 16
// 200.393 us; speedup vs baseline: 1.0292x; 1.0292x over previous
//
#include <hip/hip_runtime.h>
#include <cstdint>

#define B_    128
#define T_    2048
#define NIN_  16
#define NH_   128
#define NOUT_ 5

#define ALPHA_I_ 0.75f
#define ALPHA_V_ 0.96875f
#define THETA_   64.0f

#define NCHUNK_ 8
#define CHT_    256     // chunk size (R8/R11/R15 swept 512/128: both worse)
#define WARM_   96      // warmup timesteps (3 sub-chunks of 32)

typedef short bf16x8 __attribute__((ext_vector_type(8)));
typedef float f32x16 __attribute__((ext_vector_type(16)));
typedef int   i32x2  __attribute__((ext_vector_type(2)));

__device__ __forceinline__ float mulrn(float a, float b) { return __fmul_rn(a, b); }
__device__ __forceinline__ float addrn(float a, float b) { return __fadd_rn(a, b); }

__device__ __forceinline__ uint16_t f2bf(float x) {  // RNE f32->bf16
  uint32_t u = __float_as_uint(x);
  return (uint16_t)((u + 0x7FFFu + ((u >> 16) & 1u)) >> 16);
}

// R9: pure-VALU bit->bf16 expand. Word j carries bits 2j (lo half) and
// 2j+1 (hi half) as bf16 1.0/0.0 — zero LDS traffic in the loop.
__device__ __forceinline__ bf16x8 expand8v(uint32_t byt) {
  union { uint32_t w[4]; bf16x8 f; } r;
#pragma unroll
  for (int j = 0; j < 4; j++) {
    uint32_t b0 = (byt >> (2 * j)) & 1u;
    uint32_t b1 = (byt >> (2 * j + 1)) & 1u;
    r.w[j] = (b0 ? 0x3F80u : 0u) | (b1 ? 0x3F800000u : 0u);
  }
  return r.f;
}

// ---------------------------------------------------------------------------
// R8 merged prep+pack (one launch, 257 blocks x 1024 threads):
// blocks 0..255: pack (16 gw-groups per block); block 256: prep (R5-proven).
// ---------------------------------------------------------------------------
__global__ __launch_bounds__(1024) void prep_pack_kernel(
    const float* __restrict__ spike, uint16_t* __restrict__ Xb,
    const float* __restrict__ fc1_v, const float* __restrict__ fc1_g,
    const float* __restrict__ fc2_v, const float* __restrict__ fc2_g,
    const float* __restrict__ fc3_v, const float* __restrict__ fc3_g,
    const float* __restrict__ delay1, const float* __restrict__ delay2,
    uint16_t* __restrict__ w1swz, uint16_t* __restrict__ wswz,
    float* __restrict__ w3T, float4* __restrict__ efo1, float4* __restrict__ efo2,
    float* __restrict__ counts) {
  int tid = threadIdx.x;
  if (blockIdx.x < 256) {
    // ---- pack ----
    int gw = blockIdx.x * 16 + (tid >> 6);
    int lane = tid & 63;
    int b = gw >> 5;
    int t = (gw & 31) * 64 + lane;
    const float* sp = spike + (size_t)b * NIN_ * T_ + t;
    uint32_t mask = 0;
#pragma unroll
    for (int c = 0; c < NIN_; c++) {
      unsigned long long bal = __ballot(sp[(size_t)c * T_] != 0.f);
      mask |= (uint32_t)((bal >> lane) & 1ull) << c;
    }
    Xb[(size_t)b * T_ + t] = (uint16_t)mask;
    return;
  }
  // ---- prep (R5-proven body) ----
  __shared__ float s_n1[NH_], s_n2[NH_], s_n3[8], s_g2[NH_];
  {
    int o = tid >> 3, sub = tid & 7;  // 1024 threads -> 128 rows x 8 lanes
    float ss = 0.f;
    for (int c = sub; c < NIN_; c += 8) { float v = fc1_v[o * NIN_ + c]; ss = __fmaf_rn(v, v, ss); }
    ss += __shfl_down(ss, 4, 64); ss += __shfl_down(ss, 2, 64); ss += __shfl_down(ss, 1, 64);
    if (sub == 0) s_n1[o] = sqrtf(ss);
    float ss2 = 0.f;
    for (int c = sub; c < NH_; c += 8) { float v = fc2_v[o * NH_ + c]; ss2 = __fmaf_rn(v, v, ss2); }
    ss2 += __shfl_down(ss2, 4, 64); ss2 += __shfl_down(ss2, 2, 64); ss2 += __shfl_down(ss2, 1, 64);
    if (sub == 0) s_n2[o] = sqrtf(ss2);
  }
  if (tid < NOUT_ * 8) {
    int o = tid >> 3, sub = tid & 7;
    float ss = 0.f;
    for (int c = sub; c < NH_; c += 8) { float v = fc3_v[o * NH_ + c]; ss = __fmaf_rn(v, v, ss); }
    ss += __shfl_down(ss, 4, 64); ss += __shfl_down(ss, 2, 64); ss += __shfl_down(ss, 1, 64);
    if (sub == 0) s_n3[o] = sqrtf(ss);
  }
  if (tid < NH_) s_g2[tid] = fc2_g[tid];
  if (tid < 3) counts[tid] = 0.f;
  __syncthreads();

  if (tid < NH_) {
    float d1 = delay1[tid];
    float fl = floorf(d1);
    float f = __fsub_rn(d1, fl);
    efo1[tid] = make_float4(__int_as_float((int)fl + 1), f, __fsub_rn(1.0f, f), 0.f);
    float d2 = delay2[tid];
    float fl2 = floorf(d2);
    float f2v = __fsub_rn(d2, fl2);
    efo2[tid] = make_float4(__int_as_float((int)fl2 + 1), f2v, __fsub_rn(1.0f, f2v), 0.f);
    w3T[tid * 8 + 5] = f2v;
    w3T[tid * 8 + 6] = __fsub_rn(1.0f, f2v);
    w3T[tid * 8 + 7] = 0.f;
  }
  for (int i = tid; i < NH_ * NIN_; i += 1024) {
    int o = i >> 4, c = i & 15;
    float wv = 64.0f * __fdiv_rn(mulrn(fc1_g[o], fc1_v[i]), s_n1[o]);
    int mt = o >> 5, lane = (o & 31) + 32 * ((c >> 3) & 1), j = c & 7;
    w1swz[(mt * 64 + lane) * 8 + j] = f2bf(wv);
  }
  for (int i = tid; i < NH_ * NH_; i += 1024) {
    int o = i >> 7, c = i & 127;
    float wv = 64.0f * __fdiv_rn(mulrn(s_g2[o], fc2_v[i]), s_n2[o]);
    float d1 = delay1[c];
    float f = __fsub_rn(d1, floorf(d1));
    int lane = (o & 31) + 32 * ((c >> 3) & 1);
    int ks = c >> 4, j = c & 7, mt = o >> 5;
    wswz[((size_t)((0 * 4 + mt) * 8 + ks) * 64 + lane) * 8 + j] = f2bf(__fmul_rn(wv, f));
    wswz[((size_t)((1 * 4 + mt) * 8 + ks) * 64 + lane) * 8 + j] =
        f2bf(__fmul_rn(wv, __fsub_rn(1.0f, f)));
  }
  for (int i = tid; i < NOUT_ * NH_; i += 1024) {
    int o = i / NH_, c = i & 127;
    float wv = 64.0f * __fdiv_rn(mulrn(fc3_g[o], fc3_v[i]), s_n3[o]);
    w3T[c * 8 + o] = wv;
  }
}

// ---------------------------------------------------------------------------
// R13 interleaved gather+scan: {4 permlane -> 8 scan steps} x4 keeps only
// ev[4]+od[4] live; aA/aB die progressively. Bit-exact vs R10.
// ---------------------------------------------------------------------------
#define GATHER_AND_SCAN(aA, aB, hi, u, v, m)                               \
  {                                                                        \
    m = 0u;                                                                \
    _Pragma("unroll") for (int k = 0; k < 4; k++) {                        \
      float ev[4], od[4];                                                  \
      _Pragma("unroll") for (int i = 0; i < 4; i++) {                      \
        i32x2 pr_ = __builtin_amdgcn_permlane32_swap(                      \
            __float_as_int(aA[4 * k + i]), __float_as_int(aB[4 * k + i]),  \
            false, false);                                                 \
        ev[i] = __int_as_float(pr_[0]);                                    \
        od[i] = __int_as_float(pr_[1]);                                    \
      }                                                                    \
      _Pragma("unroll") for (int tt = 0; tt < 8; tt++) {                   \
        float z = (tt < 4) ? ev[tt & 3] : od[tt & 3];                      \
        u = addrn(mulrn(ALPHA_I_, u), z);                                  \
        v = addrn(mulrn(ALPHA_V_, v), u);                                  \
        bool sbit = (v >= THETA_);                                         \
        v = sbit ? 0.f : v;                                                \
        m |= sbit ? (1u << (8 * k + tt)) : 0u;                             \
      }                                                                    \
    }                                                                      \
  }

// ---------------------------------------------------------------------------
// R5 fused delay-shift + bit-transpose epilogue; R10 sign-bit ballot pred.
// ---------------------------------------------------------------------------
#define EMIT_PT(m, m_prev, e_o, ptw, chwstart)                             \
  {                                                                        \
    uint32_t sm = (uint32_t)((((uint64_t)(m) << 32) | (m_prev)) >> (32 - (e_o))); \
    uint32_t myword = 0u;                                                  \
    _Pragma("unroll") for (int j = 0; j < 32; j++) {                       \
      unsigned long long bal_ = __ballot((int)(sm << (31 - j)) < 0);       \
      uint32_t w_ = hi ? (uint32_t)(bal_ >> 32) : (uint32_t)bal_;          \
      myword = (tl == j) ? w_ : myword;                                    \
    }                                                                      \
    ptw[(size_t)(1 + (chwstart) + tl) * 4 + (pair * 2 + hi)] = myword;     \
  }

// ---------------------------------------------------------------------------
// Fused layer 1 (R13-proven): wave = 2 o-tiles, 2 MFMA (loop-invariant zero
// C), interleaved permlane gather + in-register scan, delay-shift+ballot-
// transpose to PT1. grid (NCHUNK_, B), block 128.
// ---------------------------------------------------------------------------
__global__ __launch_bounds__(128, 2) void fused_layer1(const uint16_t* __restrict__ Xb,
                                                       const uint16_t* __restrict__ w1swz,
                                                       const float4* __restrict__ efo,
                                                       uint32_t* __restrict__ PT1,
                                                       float* __restrict__ cnt) {
  int tid = threadIdx.x;
  int pair = tid >> 6, lane = tid & 63;
  int hi = lane >> 5, tl = lane & 31;
  int ci = blockIdx.x, b = blockIdx.y;
  const bf16x8* w1v = (const bf16x8*)w1swz;
  bf16x8 wA = w1v[(pair * 2 + 0) * 64 + lane];
  bf16x8 wB = w1v[(pair * 2 + 1) * 64 + lane];
  int e_o = __float_as_int(efo[tid].x);   // channel o = tid; e in [1,11]

  int wch = (ci == 0) ? 0 : (WARM_ / 32);
  int nch = CHT_ / 32 + wch;
  int chbase0 = ci * CHT_ - wch * 32;
  const uint16_t* xb = Xb + (size_t)b * T_;
  uint32_t* ptw = PT1 + (size_t)b * (T_ + 1) * 4;

  f32x16 zacc;
#pragma unroll
  for (int r = 0; r < 16; r++) zacc[r] = 0.f;

  float u = 0.f, v = 0.f, csum = 0.f;
  uint32_t m_prev = 0u;
  uint32_t x = xb[chbase0 + tl];
  for (int g = 0; g < nch; g++) {
    uint32_t xn = (g + 1 < nch) ? (uint32_t)xb[chbase0 + (g + 1) * 32 + tl] : 0u;
    uint32_t byt = (x >> (8 * hi)) & 0xFFu;
    bf16x8 e = expand8v(byt);
    f32x16 aA, aB;
    aA = __builtin_amdgcn_mfma_f32_32x32x16_bf16(e, wA, zacc, 0, 0, 0);
    aB = __builtin_amdgcn_mfma_f32_32x32x16_bf16(e, wB, zacc, 0, 0, 0);
    uint32_t m;
    GATHER_AND_SCAN(aA, aB, hi, u, v, m);
    if (g >= wch) {
      int chwstart = chbase0 + g * 32;
      EMIT_PT(m, m_prev, e_o, ptw, chwstart);
      int gw = chwstart >> 5;
      int pc = __popc(m);
      if (gw == 63) pc -= (int)(m >> 31);
      csum += (float)pc;
    }
    m_prev = m;
    x = xn;
  }
  if (ci == 0 && tid < 4) ptw[tid] = 0u;   // PT row 0 = zero guard
  for (int off = 32; off; off >>= 1) csum += __shfl_down(csum, off, 64);
  if (lane == 0) atomicAdd(cnt, csum);
}

// ---------------------------------------------------------------------------
// Fused layer 2 (R13-proven): wave = 2 o-tiles, baked f/(1-f) weight
// fragments in registers, 2 delay taps from PT1 rows, 4 MFMA/ks,
// interleaved permlane gather + scan, delay2-shift+transpose to PT2.
// grid (NCHUNK_, B), block 128.
// ---------------------------------------------------------------------------
__global__ __launch_bounds__(128, 2) void fused_layer2(const uint32_t* __restrict__ PT1,
                                                       const uint16_t* __restrict__ wswz,
                                                       const float4* __restrict__ efo,
                                                       uint32_t* __restrict__ PT2,
                                                       float* __restrict__ cnt) {
  int tid = threadIdx.x;
  int pair = tid >> 6, lane = tid & 63;
  int hi = lane >> 5, tl = lane & 31;
  int ci = blockIdx.x, b = blockIdx.y;
  const bf16x8* wsv = (const bf16x8*)wswz;
  int mtA = pair * 2, mtB = pair * 2 + 1;
  bf16x8 wfA[8], woA[8], wfB[8], woB[8];
#pragma unroll
  for (int ks = 0; ks < 8; ks++) {
    wfA[ks] = wsv[((size_t)((0 * 4 + mtA) * 8 + ks) * 64) + lane];
    woA[ks] = wsv[((size_t)((1 * 4 + mtA) * 8 + ks) * 64) + lane];
    wfB[ks] = wsv[((size_t)((0 * 4 + mtB) * 8 + ks) * 64) + lane];
    woB[ks] = wsv[((size_t)((1 * 4 + mtB) * 8 + ks) * 64) + lane];
  }
  int e_o = __float_as_int(efo[tid].x);   // channel o = tid; e in [1,11]

  int wch = (ci == 0) ? 0 : (WARM_ / 32);
  int nch = CHT_ / 32 + wch;
  int chbase0 = ci * CHT_ - wch * 32;
  const uint4* pt = (const uint4*)PT1 + (size_t)b * (T_ + 1);
  uint32_t* ptw = PT2 + (size_t)b * (T_ + 1) * 4;

  float u = 0.f, v = 0.f, csum = 0.f;
  uint32_t m_prev = 0u;
  uint4 R0 = pt[chbase0 + tl];
  uint4 R1 = pt[chbase0 + tl + 1];
  for (int g = 0; g < nch; g++) {
    uint4 R0n = R0, R1n = R1;
    if (g + 1 < nch) {
      R0n = pt[chbase0 + (g + 1) * 32 + tl];
      R1n = pt[chbase0 + (g + 1) * 32 + tl + 1];
    }
    uint32_t r0w[4] = {R0.x, R0.y, R0.z, R0.w};
    uint32_t r1w[4] = {R1.x, R1.y, R1.z, R1.w};
    f32x16 aA, aB;
#pragma unroll
    for (int r = 0; r < 16; r++) { aA[r] = 0.f; aB[r] = 0.f; }
#pragma unroll
    for (int ks = 0; ks < 8; ks++) {
      int sh = 16 * (ks & 1) + 8 * hi;
      uint32_t b0 = (r0w[ks >> 1] >> sh) & 0xFFu;  // tap s[t-e-1] -> Wf
      uint32_t b1 = (r1w[ks >> 1] >> sh) & 0xFFu;  // tap s[t-e]   -> Wof
      bf16x8 e0 = expand8v(b0);
      bf16x8 e1 = expand8v(b1);
      aA = __builtin_amdgcn_mfma_f32_32x32x16_bf16(e0, wfA[ks], aA, 0, 0, 0);
      aA = __builtin_amdgcn_mfma_f32_32x32x16_bf16(e1, woA[ks], aA, 0, 0, 0);
      aB = __builtin_amdgcn_mfma_f32_32x32x16_bf16(e0, wfB[ks], aB, 0, 0, 0);
      aB = __builtin_amdgcn_mfma_f32_32x32x16_bf16(e1, woB[ks], aB, 0, 0, 0);
    }
    uint32_t m;
    GATHER_AND_SCAN(aA, aB, hi, u, v, m);
    if (g >= wch) {
      int chwstart = chbase0 + g * 32;
      EMIT_PT(m, m_prev, e_o, ptw, chwstart);
      int gw = chwstart >> 5;
      int pc = __popc(m);
      if (gw == 63) pc -= (int)(m >> 31);
      csum += (float)pc;
    }
    m_prev = m;
    R0 = R0n; R1 = R1n;
  }
  if (ci == 0 && tid < 4) ptw[tid] = 0u;   // PT row 0 = zero guard
  for (int off = 32; off; off >>= 1) csum += __shfl_down(csum, off, 64);
  if (lane == 0) atomicAdd(cnt, csum);
}

// ---------------------------------------------------------------------------
// gemm3 (R16: w3T staged in LDS — the 128-iteration inner loop previously
// re-issued ~900 uniform s_loads/pass with ~200-cy SMEM latency and poor
// hiding at 4 waves/SIMD; LDS broadcast reads are conflict-free and
// pipelined. Same values, same accumulation order — bit-identical).
// ---------------------------------------------------------------------------
__global__ __launch_bounds__(256) void gemm3_kernel(const uint32_t* __restrict__ PTpad,
                                                    const float* __restrict__ w3T,
                                                    float* __restrict__ z) {
  __shared__ float s_w[NH_ * 8];
  int tid = threadIdx.x;
  for (int i = tid; i < NH_ * 8; i += 256) s_w[i] = w3T[i];
  __syncthreads();

  int t = blockIdx.x * 256 + tid;
  int b = blockIdx.y;
  const uint4* pt = (const uint4*)PTpad + (size_t)b * (T_ + 1);
  uint4 R0 = pt[t];
  uint4 R1 = pt[t + 1];
  uint32_t r0w[4] = {R0.x, R0.y, R0.z, R0.w};
  uint32_t r1w[4] = {R1.x, R1.y, R1.z, R1.w};

  float acc[NOUT_];
#pragma unroll
  for (int o = 0; o < NOUT_; o++) acc[o] = 0.f;

#pragma unroll
  for (int c = 0; c < NH_; c++) {
    const float* wc = s_w + (c << 3);
    float f = wc[5], omf = wc[6];
    float fb0 = (float)((r0w[c >> 5] >> (c & 31)) & 1u);
    float fb1 = (float)((r1w[c >> 5] >> (c & 31)) & 1u);
    float val = __fmaf_rn(omf, fb1, __fmul_rn(f, fb0));
#pragma unroll
    for (int o = 0; o < NOUT_; o++) acc[o] = __fmaf_rn(wc[o], val, acc[o]);
  }

#pragma unroll
  for (int o = 0; o < NOUT_; o++)
    z[((size_t)b * NOUT_ + o) * T_ + t] = acc[o];
}

// ---------------------------------------------------------------------------
// Chunked layer-3 scan (R14-proven: 8 chunks x 256 t, block 64, grid 80;
// per-thread work and arithmetic byte-identical to the R5 version).
// ---------------------------------------------------------------------------
__global__ __launch_bounds__(64) void scan3_kernel(const float* __restrict__ z3,
                                                   float* __restrict__ out,
                                                   float* __restrict__ cnt) {
  int id = blockIdx.x * 64 + threadIdx.x;
  int row = id % (B_ * NOUT_);
  int ci = id / (B_ * NOUT_);
  int tstart = ci * CHT_;
  int t0 = (ci == 0) ? 0 : tstart - WARM_;
  const float4* zp4 = (const float4*)(z3 + (size_t)row * T_);

  float u = 0.f, v = 0.f, carry = 0.f;
  int cnt_i = 0;
  for (int gg = t0 / 16; gg < tstart / 16; gg++) {
#pragma unroll
    for (int q = 0; q < 4; q++) {
      float4 cv = zp4[gg * 4 + q];
      float zv[4] = {cv.x, cv.y, cv.z, cv.w};
#pragma unroll
      for (int j = 0; j < 4; j++) {
        u = addrn(mulrn(ALPHA_I_, u), zv[j]);
        v = addrn(mulrn(ALPHA_V_, v), u);
        bool s = (v >= THETA_);
        v = s ? 0.f : v;
        carry = s ? 1.f : 0.f;
      }
    }
  }
  float4* op4 = (float4*)(out + (size_t)row * T_ + tstart);
  for (int gg = 0; gg < CHT_ / 16; gg++) {
    float sarr[16];
#pragma unroll
    for (int q = 0; q < 4; q++) {
      float4 cv = zp4[(tstart / 16 + gg) * 4 + q];
      float zv[4] = {cv.x, cv.y, cv.z, cv.w};
#pragma unroll
      for (int j = 0; j < 4; j++) {
        u = addrn(mulrn(ALPHA_I_, u), zv[j]);
        v = addrn(mulrn(ALPHA_V_, v), u);
        bool s = (v >= THETA_);
        v = s ? 0.f : v;
        sarr[q * 4 + j] = s ? 1.f : 0.f;
      }
    }
#pragma unroll
    for (int k = 0; k < 16; k++) {
      int t = tstart + gg * 16 + k;
      if (t < T_ - 1) cnt_i += (sarr[k] != 0.f) ? 1 : 0;
    }
    op4[gg * 4 + 0] = make_float4(carry, sarr[0], sarr[1], sarr[2]);
    op4[gg * 4 + 1] = make_float4(sarr[3], sarr[4], sarr[5], sarr[6]);
    op4[gg * 4 + 2] = make_float4(sarr[7], sarr[8], sarr[9], sarr[10]);
    op4[gg * 4 + 3] = make_float4(sarr[11], sarr[12], sarr[13], sarr[14]);
    carry = sarr[15];
  }
  float c = (float)cnt_i;
  for (int off = 32; off; off >>= 1) c += __shfl_down(c, off, 64);
  if ((threadIdx.x & 63) == 0) atomicAdd(cnt, c);
}

// ---------------------------------------------------------------------------
extern "C" void kernel_launch(void* const* d_in, const int* in_sizes, int n_in,
                              void* d_out, int out_size, void* d_ws, size_t ws_size,
                              hipStream_t stream) {
  (void)in_sizes; (void)n_in; (void)out_size; (void)ws_size;
  const float* spike  = (const float*)d_in[0];
  const float* fc1_v  = (const float*)d_in[1];
  const float* fc1_g  = (const float*)d_in[2];
  const float* fc2_v  = (const float*)d_in[3];
  const float* fc2_g  = (const float*)d_in[4];
  const float* fc3_v  = (const float*)d_in[5];
  const float* fc3_g  = (const float*)d_in[6];
  const float* delay1 = (const float*)d_in[7];
  const float* delay2 = (const float*)d_in[8];
  float* out = (float*)d_out;

  float* ws = (float*)d_ws;
  float* w3T       = ws;                         // 1024 f
  float4* efo1     = (float4*)(ws + 1024);       // 512 f
  float4* efo2     = (float4*)(ws + 1536);       // 512 f
  uint16_t* w1swz  = (uint16_t*)(ws + 2048);     // 2048 u16 = 1024 f
  uint16_t* wswz   = (uint16_t*)(ws + 3072);     // 32768 u16 = 16384 f
  uint16_t* Xb     = (uint16_t*)(ws + 19456);    // B*T u16 = 131072 f
  uint32_t* PT1    = (uint32_t*)(ws + 150528);   // B*(T+1)*4 u32 (layer1 out)
  uint32_t* PT2    = (uint32_t*)(ws + 1264640);  // B*(T+1)*4 u32 (layer2 out)
  float* z3        = ws + 2313728;               // B*5*T f32
  float* counts = out + (size_t)B_ * NOUT_ * T_;

  prep_pack_kernel<<<dim3(257), 1024, 0, stream>>>(
      spike, Xb, fc1_v, fc1_g, fc2_v, fc2_g, fc3_v, fc3_g,
      delay1, delay2, w1swz, wswz, w3T, efo1, efo2, counts);

  fused_layer1<<<dim3(NCHUNK_, B_), 128, 0, stream>>>(Xb, w1swz, efo1, PT1, counts + 0);

  fused_layer2<<<dim3(NCHUNK_, B_), 128, 0, stream>>>(PT1, wswz, efo2, PT2, counts + 1);

  gemm3_kernel<<<dim3(T_ / 256, B_), 256, 0, stream>>>(PT2, w3T, z3);
  scan3_kernel<<<dim3(NCHUNK_ * B_ * NOUT_ / 64), 64, 0, stream>>>(z3, out, counts + 2);
}

// Round 17
// 193.000 us; speedup vs baseline: 1.0686x; 1.0383x over previous
//
#include <hip/hip_runtime.h>
#include <cstdint>

#define B_    128
#define T_    2048
#define NIN_  16
#define NH_   128
#define NOUT_ 5

#define ALPHA_I_ 0.75f
#define ALPHA_V_ 0.96875f
#define THETA_   64.0f

#define NCHUNK_ 8
#define CHT_    256     // chunk size (R8/R11/R15 swept 512/128: both worse)
#define WARM_   96      // warmup timesteps (3 sub-chunks of 32)

typedef short bf16x8 __attribute__((ext_vector_type(8)));
typedef float f32x16 __attribute__((ext_vector_type(16)));
typedef int   i32x2  __attribute__((ext_vector_type(2)));

__device__ __forceinline__ float mulrn(float a, float b) { return __fmul_rn(a, b); }
__device__ __forceinline__ float addrn(float a, float b) { return __fadd_rn(a, b); }

__device__ __forceinline__ uint16_t f2bf(float x) {  // RNE f32->bf16
  uint32_t u = __float_as_uint(x);
  return (uint16_t)((u + 0x7FFFu + ((u >> 16) & 1u)) >> 16);
}

// R9: pure-VALU bit->bf16 expand. Word j carries bits 2j (lo half) and
// 2j+1 (hi half) as bf16 1.0/0.0 — zero LDS traffic in the loop.
__device__ __forceinline__ bf16x8 expand8v(uint32_t byt) {
  union { uint32_t w[4]; bf16x8 f; } r;
#pragma unroll
  for (int j = 0; j < 4; j++) {
    uint32_t b0 = (byt >> (2 * j)) & 1u;
    uint32_t b1 = (byt >> (2 * j + 1)) & 1u;
    r.w[j] = (b0 ? 0x3F80u : 0u) | (b1 ? 0x3F800000u : 0u);
  }
  return r.f;
}

// ---------------------------------------------------------------------------
// R8 merged prep+pack (one launch, 257 blocks x 1024 threads):
// blocks 0..255: pack (16 gw-groups per block); block 256: prep (R5-proven).
// ---------------------------------------------------------------------------
__global__ __launch_bounds__(1024) void prep_pack_kernel(
    const float* __restrict__ spike, uint16_t* __restrict__ Xb,
    const float* __restrict__ fc1_v, const float* __restrict__ fc1_g,
    const float* __restrict__ fc2_v, const float* __restrict__ fc2_g,
    const float* __restrict__ fc3_v, const float* __restrict__ fc3_g,
    const float* __restrict__ delay1, const float* __restrict__ delay2,
    uint16_t* __restrict__ w1swz, uint16_t* __restrict__ wswz,
    float* __restrict__ w3T, float4* __restrict__ efo1, float4* __restrict__ efo2,
    float* __restrict__ counts) {
  int tid = threadIdx.x;
  if (blockIdx.x < 256) {
    // ---- pack ----
    int gw = blockIdx.x * 16 + (tid >> 6);
    int lane = tid & 63;
    int b = gw >> 5;
    int t = (gw & 31) * 64 + lane;
    const float* sp = spike + (size_t)b * NIN_ * T_ + t;
    uint32_t mask = 0;
#pragma unroll
    for (int c = 0; c < NIN_; c++) {
      unsigned long long bal = __ballot(sp[(size_t)c * T_] != 0.f);
      mask |= (uint32_t)((bal >> lane) & 1ull) << c;
    }
    Xb[(size_t)b * T_ + t] = (uint16_t)mask;
    return;
  }
  // ---- prep (R5-proven body) ----
  __shared__ float s_n1[NH_], s_n2[NH_], s_n3[8], s_g2[NH_];
  {
    int o = tid >> 3, sub = tid & 7;  // 1024 threads -> 128 rows x 8 lanes
    float ss = 0.f;
    for (int c = sub; c < NIN_; c += 8) { float v = fc1_v[o * NIN_ + c]; ss = __fmaf_rn(v, v, ss); }
    ss += __shfl_down(ss, 4, 64); ss += __shfl_down(ss, 2, 64); ss += __shfl_down(ss, 1, 64);
    if (sub == 0) s_n1[o] = sqrtf(ss);
    float ss2 = 0.f;
    for (int c = sub; c < NH_; c += 8) { float v = fc2_v[o * NH_ + c]; ss2 = __fmaf_rn(v, v, ss2); }
    ss2 += __shfl_down(ss2, 4, 64); ss2 += __shfl_down(ss2, 2, 64); ss2 += __shfl_down(ss2, 1, 64);
    if (sub == 0) s_n2[o] = sqrtf(ss2);
  }
  if (tid < NOUT_ * 8) {
    int o = tid >> 3, sub = tid & 7;
    float ss = 0.f;
    for (int c = sub; c < NH_; c += 8) { float v = fc3_v[o * NH_ + c]; ss = __fmaf_rn(v, v, ss); }
    ss += __shfl_down(ss, 4, 64); ss += __shfl_down(ss, 2, 64); ss += __shfl_down(ss, 1, 64);
    if (sub == 0) s_n3[o] = sqrtf(ss);
  }
  if (tid < NH_) s_g2[tid] = fc2_g[tid];
  if (tid < 3) counts[tid] = 0.f;
  __syncthreads();

  if (tid < NH_) {
    float d1 = delay1[tid];
    float fl = floorf(d1);
    float f = __fsub_rn(d1, fl);
    efo1[tid] = make_float4(__int_as_float((int)fl + 1), f, __fsub_rn(1.0f, f), 0.f);
    float d2 = delay2[tid];
    float fl2 = floorf(d2);
    float f2v = __fsub_rn(d2, fl2);
    efo2[tid] = make_float4(__int_as_float((int)fl2 + 1), f2v, __fsub_rn(1.0f, f2v), 0.f);
    w3T[tid * 8 + 5] = f2v;
    w3T[tid * 8 + 6] = __fsub_rn(1.0f, f2v);
    w3T[tid * 8 + 7] = 0.f;
  }
  for (int i = tid; i < NH_ * NIN_; i += 1024) {
    int o = i >> 4, c = i & 15;
    float wv = 64.0f * __fdiv_rn(mulrn(fc1_g[o], fc1_v[i]), s_n1[o]);
    int mt = o >> 5, lane = (o & 31) + 32 * ((c >> 3) & 1), j = c & 7;
    w1swz[(mt * 64 + lane) * 8 + j] = f2bf(wv);
  }
  for (int i = tid; i < NH_ * NH_; i += 1024) {
    int o = i >> 7, c = i & 127;
    float wv = 64.0f * __fdiv_rn(mulrn(s_g2[o], fc2_v[i]), s_n2[o]);
    float d1 = delay1[c];
    float f = __fsub_rn(d1, floorf(d1));
    int lane = (o & 31) + 32 * ((c >> 3) & 1);
    int ks = c >> 4, j = c & 7, mt = o >> 5;
    wswz[((size_t)((0 * 4 + mt) * 8 + ks) * 64 + lane) * 8 + j] = f2bf(__fmul_rn(wv, f));
    wswz[((size_t)((1 * 4 + mt) * 8 + ks) * 64 + lane) * 8 + j] =
        f2bf(__fmul_rn(wv, __fsub_rn(1.0f, f)));
  }
  for (int i = tid; i < NOUT_ * NH_; i += 1024) {
    int o = i / NH_, c = i & 127;
    float wv = 64.0f * __fdiv_rn(mulrn(fc3_g[o], fc3_v[i]), s_n3[o]);
    w3T[c * 8 + o] = wv;
  }
}

// ---------------------------------------------------------------------------
// R13 interleaved gather+scan: {4 permlane -> 8 scan steps} x4 keeps only
// ev[4]+od[4] live; aA/aB die progressively. Bit-exact vs R10.
// ---------------------------------------------------------------------------
#define GATHER_AND_SCAN(aA, aB, hi, u, v, m)                               \
  {                                                                        \
    m = 0u;                                                                \
    _Pragma("unroll") for (int k = 0; k < 4; k++) {                        \
      float ev[4], od[4];                                                  \
      _Pragma("unroll") for (int i = 0; i < 4; i++) {                      \
        i32x2 pr_ = __builtin_amdgcn_permlane32_swap(                      \
            __float_as_int(aA[4 * k + i]), __float_as_int(aB[4 * k + i]),  \
            false, false);                                                 \
        ev[i] = __int_as_float(pr_[0]);                                    \
        od[i] = __int_as_float(pr_[1]);                                    \
      }                                                                    \
      _Pragma("unroll") for (int tt = 0; tt < 8; tt++) {                   \
        float z = (tt < 4) ? ev[tt & 3] : od[tt & 3];                      \
        u = addrn(mulrn(ALPHA_I_, u), z);                                  \
        v = addrn(mulrn(ALPHA_V_, v), u);                                  \
        bool sbit = (v >= THETA_);                                         \
        v = sbit ? 0.f : v;                                                \
        m |= sbit ? (1u << (8 * k + tt)) : 0u;                             \
      }                                                                    \
    }                                                                      \
  }

// ---------------------------------------------------------------------------
// R5 fused delay-shift + bit-transpose epilogue; R10 sign-bit ballot pred.
// ---------------------------------------------------------------------------
#define EMIT_PT(m, m_prev, e_o, ptw, chwstart)                             \
  {                                                                        \
    uint32_t sm = (uint32_t)((((uint64_t)(m) << 32) | (m_prev)) >> (32 - (e_o))); \
    uint32_t myword = 0u;                                                  \
    _Pragma("unroll") for (int j = 0; j < 32; j++) {                       \
      unsigned long long bal_ = __ballot((int)(sm << (31 - j)) < 0);       \
      uint32_t w_ = hi ? (uint32_t)(bal_ >> 32) : (uint32_t)bal_;          \
      myword = (tl == j) ? w_ : myword;                                    \
    }                                                                      \
    ptw[(size_t)(1 + (chwstart) + tl) * 4 + (pair * 2 + hi)] = myword;     \
  }

// ---------------------------------------------------------------------------
// Fused layer 1 (R13-proven): wave = 2 o-tiles, 2 MFMA (loop-invariant zero
// C), interleaved permlane gather + in-register scan, delay-shift+ballot-
// transpose to PT1. grid (NCHUNK_, B), block 128.
// ---------------------------------------------------------------------------
__global__ __launch_bounds__(128, 2) void fused_layer1(const uint16_t* __restrict__ Xb,
                                                       const uint16_t* __restrict__ w1swz,
                                                       const float4* __restrict__ efo,
                                                       uint32_t* __restrict__ PT1,
                                                       float* __restrict__ cnt) {
  int tid = threadIdx.x;
  int pair = tid >> 6, lane = tid & 63;
  int hi = lane >> 5, tl = lane & 31;
  int ci = blockIdx.x, b = blockIdx.y;
  const bf16x8* w1v = (const bf16x8*)w1swz;
  bf16x8 wA = w1v[(pair * 2 + 0) * 64 + lane];
  bf16x8 wB = w1v[(pair * 2 + 1) * 64 + lane];
  int e_o = __float_as_int(efo[tid].x);   // channel o = tid; e in [1,11]

  int wch = (ci == 0) ? 0 : (WARM_ / 32);
  int nch = CHT_ / 32 + wch;
  int chbase0 = ci * CHT_ - wch * 32;
  const uint16_t* xb = Xb + (size_t)b * T_;
  uint32_t* ptw = PT1 + (size_t)b * (T_ + 1) * 4;

  f32x16 zacc;
#pragma unroll
  for (int r = 0; r < 16; r++) zacc[r] = 0.f;

  float u = 0.f, v = 0.f, csum = 0.f;
  uint32_t m_prev = 0u;
  uint32_t x = xb[chbase0 + tl];
  for (int g = 0; g < nch; g++) {
    uint32_t xn = (g + 1 < nch) ? (uint32_t)xb[chbase0 + (g + 1) * 32 + tl] : 0u;
    uint32_t byt = (x >> (8 * hi)) & 0xFFu;
    bf16x8 e = expand8v(byt);
    f32x16 aA, aB;
    aA = __builtin_amdgcn_mfma_f32_32x32x16_bf16(e, wA, zacc, 0, 0, 0);
    aB = __builtin_amdgcn_mfma_f32_32x32x16_bf16(e, wB, zacc, 0, 0, 0);
    uint32_t m;
    GATHER_AND_SCAN(aA, aB, hi, u, v, m);
    if (g >= wch) {
      int chwstart = chbase0 + g * 32;
      EMIT_PT(m, m_prev, e_o, ptw, chwstart);
      int gw = chwstart >> 5;
      int pc = __popc(m);
      if (gw == 63) pc -= (int)(m >> 31);
      csum += (float)pc;
    }
    m_prev = m;
    x = xn;
  }
  if (ci == 0 && tid < 4) ptw[tid] = 0u;   // PT row 0 = zero guard
  for (int off = 32; off; off >>= 1) csum += __shfl_down(csum, off, 64);
  if (lane == 0) atomicAdd(cnt, csum);
}

// ---------------------------------------------------------------------------
// Fused layer 2 (R13-proven): wave = 2 o-tiles, baked f/(1-f) weight
// fragments in registers, 2 delay taps from PT1 rows, 4 MFMA/ks,
// interleaved permlane gather + scan, delay2-shift+transpose to PT2.
// grid (NCHUNK_, B), block 128.
// ---------------------------------------------------------------------------
__global__ __launch_bounds__(128, 2) void fused_layer2(const uint32_t* __restrict__ PT1,
                                                       const uint16_t* __restrict__ wswz,
                                                       const float4* __restrict__ efo,
                                                       uint32_t* __restrict__ PT2,
                                                       float* __restrict__ cnt) {
  int tid = threadIdx.x;
  int pair = tid >> 6, lane = tid & 63;
  int hi = lane >> 5, tl = lane & 31;
  int ci = blockIdx.x, b = blockIdx.y;
  const bf16x8* wsv = (const bf16x8*)wswz;
  int mtA = pair * 2, mtB = pair * 2 + 1;
  bf16x8 wfA[8], woA[8], wfB[8], woB[8];
#pragma unroll
  for (int ks = 0; ks < 8; ks++) {
    wfA[ks] = wsv[((size_t)((0 * 4 + mtA) * 8 + ks) * 64) + lane];
    woA[ks] = wsv[((size_t)((1 * 4 + mtA) * 8 + ks) * 64) + lane];
    wfB[ks] = wsv[((size_t)((0 * 4 + mtB) * 8 + ks) * 64) + lane];
    woB[ks] = wsv[((size_t)((1 * 4 + mtB) * 8 + ks) * 64) + lane];
  }
  int e_o = __float_as_int(efo[tid].x);   // channel o = tid; e in [1,11]

  int wch = (ci == 0) ? 0 : (WARM_ / 32);
  int nch = CHT_ / 32 + wch;
  int chbase0 = ci * CHT_ - wch * 32;
  const uint4* pt = (const uint4*)PT1 + (size_t)b * (T_ + 1);
  uint32_t* ptw = PT2 + (size_t)b * (T_ + 1) * 4;

  float u = 0.f, v = 0.f, csum = 0.f;
  uint32_t m_prev = 0u;
  uint4 R0 = pt[chbase0 + tl];
  uint4 R1 = pt[chbase0 + tl + 1];
  for (int g = 0; g < nch; g++) {
    uint4 R0n = R0, R1n = R1;
    if (g + 1 < nch) {
      R0n = pt[chbase0 + (g + 1) * 32 + tl];
      R1n = pt[chbase0 + (g + 1) * 32 + tl + 1];
    }
    uint32_t r0w[4] = {R0.x, R0.y, R0.z, R0.w};
    uint32_t r1w[4] = {R1.x, R1.y, R1.z, R1.w};
    f32x16 aA, aB;
#pragma unroll
    for (int r = 0; r < 16; r++) { aA[r] = 0.f; aB[r] = 0.f; }
#pragma unroll
    for (int ks = 0; ks < 8; ks++) {
      int sh = 16 * (ks & 1) + 8 * hi;
      uint32_t b0 = (r0w[ks >> 1] >> sh) & 0xFFu;  // tap s[t-e-1] -> Wf
      uint32_t b1 = (r1w[ks >> 1] >> sh) & 0xFFu;  // tap s[t-e]   -> Wof
      bf16x8 e0 = expand8v(b0);
      bf16x8 e1 = expand8v(b1);
      aA = __builtin_amdgcn_mfma_f32_32x32x16_bf16(e0, wfA[ks], aA, 0, 0, 0);
      aA = __builtin_amdgcn_mfma_f32_32x32x16_bf16(e1, woA[ks], aA, 0, 0, 0);
      aB = __builtin_amdgcn_mfma_f32_32x32x16_bf16(e0, wfB[ks], aB, 0, 0, 0);
      aB = __builtin_amdgcn_mfma_f32_32x32x16_bf16(e1, woB[ks], aB, 0, 0, 0);
    }
    uint32_t m;
    GATHER_AND_SCAN(aA, aB, hi, u, v, m);
    if (g >= wch) {
      int chwstart = chbase0 + g * 32;
      EMIT_PT(m, m_prev, e_o, ptw, chwstart);
      int gw = chwstart >> 5;
      int pc = __popc(m);
      if (gw == 63) pc -= (int)(m >> 31);
      csum += (float)pc;
    }
    m_prev = m;
    R0 = R0n; R1 = R1n;
  }
  if (ci == 0 && tid < 4) ptw[tid] = 0u;   // PT row 0 = zero guard
  for (int off = 32; off; off >>= 1) csum += __shfl_down(csum, off, 64);
  if (lane == 0) atomicAdd(cnt, csum);
}

// ---------------------------------------------------------------------------
// gemm3 (R17: per-nibble LUT — acc[o] = sum over 32 nibble-groups of
// LUTf[np][nib0][o] + LUTo[np][nib1][o]; LUT entry = 4-bit dot of the
// group's (f or 1-f)-scaled W3 slice. 32KB LDS, built once per block.
// Cuts per-thread LDS ops 896 -> 128 and VALU ~2x vs per-channel loop.
// Same f32 products, re-associated sums (smaller perturbation than R6's
// bf16 re-rounding, which passed).
// ---------------------------------------------------------------------------
__global__ __launch_bounds__(256) void gemm3_kernel(const uint32_t* __restrict__ PTpad,
                                                    const float* __restrict__ w3T,
                                                    float* __restrict__ z) {
  __shared__ float s_lut[2 * 32 * 16 * 8];   // [tap][np][nib][8] (5 used)
  int tid = threadIdx.x;
  for (int e = tid; e < 2 * 32 * 16; e += 256) {
    int tap = e >> 9, rem = e & 511, np = rem >> 4, nib = rem & 15;
    float a0 = 0.f, a1 = 0.f, a2 = 0.f, a3 = 0.f, a4 = 0.f;
#pragma unroll
    for (int j = 0; j < 4; j++) {
      if ((nib >> j) & 1) {
        int c = np * 4 + j;
        float fs = w3T[c * 8 + (tap ? 6 : 5)];
        a0 = __fmaf_rn(__fmul_rn(w3T[c * 8 + 0], fs), 1.0f, a0);
        a1 = __fmaf_rn(__fmul_rn(w3T[c * 8 + 1], fs), 1.0f, a1);
        a2 = __fmaf_rn(__fmul_rn(w3T[c * 8 + 2], fs), 1.0f, a2);
        a3 = __fmaf_rn(__fmul_rn(w3T[c * 8 + 3], fs), 1.0f, a3);
        a4 = __fmaf_rn(__fmul_rn(w3T[c * 8 + 4], fs), 1.0f, a4);
      }
    }
    float* dst = s_lut + e * 8;
    dst[0] = a0; dst[1] = a1; dst[2] = a2; dst[3] = a3; dst[4] = a4;
    dst[5] = 0.f; dst[6] = 0.f; dst[7] = 0.f;
  }
  __syncthreads();

  int t = blockIdx.x * 256 + tid;
  int b = blockIdx.y;
  const uint4* pt = (const uint4*)PTpad + (size_t)b * (T_ + 1);
  uint4 R0 = pt[t];
  uint4 R1 = pt[t + 1];
  uint32_t r0w[4] = {R0.x, R0.y, R0.z, R0.w};
  uint32_t r1w[4] = {R1.x, R1.y, R1.z, R1.w};

  float acc0 = 0.f, acc1 = 0.f, acc2 = 0.f, acc3 = 0.f, acc4 = 0.f;
#pragma unroll
  for (int np = 0; np < 32; np++) {
    uint32_t nib0 = (r0w[np >> 3] >> ((np & 7) * 4)) & 15u;
    uint32_t nib1 = (r1w[np >> 3] >> ((np & 7) * 4)) & 15u;
    const float* e0 = s_lut + ((np * 16 + (int)nib0) << 3);
    const float* e1 = s_lut + ((512 * 8) >> 3 << 3) + (((512 + np * 16 + (int)nib1) - 512) << 3) + 512 * 8 - 512 * 8;  // placeholder avoided below
    e1 = s_lut + ((512 + np * 16 + (int)nib1) << 3);
    float4 v0 = *(const float4*)(e0);
    float w40 = e0[4];
    float4 v1 = *(const float4*)(e1);
    float w41 = e1[4];
    acc0 = addrn(acc0, addrn(v0.x, v1.x));
    acc1 = addrn(acc1, addrn(v0.y, v1.y));
    acc2 = addrn(acc2, addrn(v0.z, v1.z));
    acc3 = addrn(acc3, addrn(v0.w, v1.w));
    acc4 = addrn(acc4, addrn(w40, w41));
  }

  z[((size_t)b * NOUT_ + 0) * T_ + t] = acc0;
  z[((size_t)b * NOUT_ + 1) * T_ + t] = acc1;
  z[((size_t)b * NOUT_ + 2) * T_ + t] = acc2;
  z[((size_t)b * NOUT_ + 3) * T_ + t] = acc3;
  z[((size_t)b * NOUT_ + 4) * T_ + t] = acc4;
}

// ---------------------------------------------------------------------------
// Chunked layer-3 scan (R14-proven: 8 chunks x 256 t, block 64, grid 80;
// per-thread work and arithmetic byte-identical to the R5 version).
// ---------------------------------------------------------------------------
__global__ __launch_bounds__(64) void scan3_kernel(const float* __restrict__ z3,
                                                   float* __restrict__ out,
                                                   float* __restrict__ cnt) {
  int id = blockIdx.x * 64 + threadIdx.x;
  int row = id % (B_ * NOUT_);
  int ci = id / (B_ * NOUT_);
  int tstart = ci * CHT_;
  int t0 = (ci == 0) ? 0 : tstart - WARM_;
  const float4* zp4 = (const float4*)(z3 + (size_t)row * T_);

  float u = 0.f, v = 0.f, carry = 0.f;
  int cnt_i = 0;
  for (int gg = t0 / 16; gg < tstart / 16; gg++) {
#pragma unroll
    for (int q = 0; q < 4; q++) {
      float4 cv = zp4[gg * 4 + q];
      float zv[4] = {cv.x, cv.y, cv.z, cv.w};
#pragma unroll
      for (int j = 0; j < 4; j++) {
        u = addrn(mulrn(ALPHA_I_, u), zv[j]);
        v = addrn(mulrn(ALPHA_V_, v), u);
        bool s = (v >= THETA_);
        v = s ? 0.f : v;
        carry = s ? 1.f : 0.f;
      }
    }
  }
  float4* op4 = (float4*)(out + (size_t)row * T_ + tstart);
  for (int gg = 0; gg < CHT_ / 16; gg++) {
    float sarr[16];
#pragma unroll
    for (int q = 0; q < 4; q++) {
      float4 cv = zp4[(tstart / 16 + gg) * 4 + q];
      float zv[4] = {cv.x, cv.y, cv.z, cv.w};
#pragma unroll
      for (int j = 0; j < 4; j++) {
        u = addrn(mulrn(ALPHA_I_, u), zv[j]);
        v = addrn(mulrn(ALPHA_V_, v), u);
        bool s = (v >= THETA_);
        v = s ? 0.f : v;
        sarr[q * 4 + j] = s ? 1.f : 0.f;
      }
    }
#pragma unroll
    for (int k = 0; k < 16; k++) {
      int t = tstart + gg * 16 + k;
      if (t < T_ - 1) cnt_i += (sarr[k] != 0.f) ? 1 : 0;
    }
    op4[gg * 4 + 0] = make_float4(carry, sarr[0], sarr[1], sarr[2]);
    op4[gg * 4 + 1] = make_float4(sarr[3], sarr[4], sarr[5], sarr[6]);
    op4[gg * 4 + 2] = make_float4(sarr[7], sarr[8], sarr[9], sarr[10]);
    op4[gg * 4 + 3] = make_float4(sarr[11], sarr[12], sarr[13], sarr[14]);
    carry = sarr[15];
  }
  float c = (float)cnt_i;
  for (int off = 32; off; off >>= 1) c += __shfl_down(c, off, 64);
  if ((threadIdx.x & 63) == 0) atomicAdd(cnt, c);
}

// ---------------------------------------------------------------------------
extern "C" void kernel_launch(void* const* d_in, const int* in_sizes, int n_in,
                              void* d_out, int out_size, void* d_ws, size_t ws_size,
                              hipStream_t stream) {
  (void)in_sizes; (void)n_in; (void)out_size; (void)ws_size;
  const float* spike  = (const float*)d_in[0];
  const float* fc1_v  = (const float*)d_in[1];
  const float* fc1_g  = (const float*)d_in[2];
  const float* fc2_v  = (const float*)d_in[3];
  const float* fc2_g  = (const float*)d_in[4];
  const float* fc3_v  = (const float*)d_in[5];
  const float* fc3_g  = (const float*)d_in[6];
  const float* delay1 = (const float*)d_in[7];
  const float* delay2 = (const float*)d_in[8];
  float* out = (float*)d_out;

  float* ws = (float*)d_ws;
  float* w3T       = ws;                         // 1024 f
  float4* efo1     = (float4*)(ws + 1024);       // 512 f
  float4* efo2     = (float4*)(ws + 1536);       // 512 f
  uint16_t* w1swz  = (uint16_t*)(ws + 2048);     // 2048 u16 = 1024 f
  uint16_t* wswz   = (uint16_t*)(ws + 3072);     // 32768 u16 = 16384 f
  uint16_t* Xb     = (uint16_t*)(ws + 19456);    // B*T u16 = 131072 f
  uint32_t* PT1    = (uint32_t*)(ws + 150528);   // B*(T+1)*4 u32 (layer1 out)
  uint32_t* PT2    = (uint32_t*)(ws + 1264640);  // B*(T+1)*4 u32 (layer2 out)
  float* z3        = ws + 2313728;               // B*5*T f32
  float* counts = out + (size_t)B_ * NOUT_ * T_;

  prep_pack_kernel<<<dim3(257), 1024, 0, stream>>>(
      spike, Xb, fc1_v, fc1_g, fc2_v, fc2_g, fc3_v, fc3_g,
      delay1, delay2, w1swz, wswz, w3T, efo1, efo2, counts);

  fused_layer1<<<dim3(NCHUNK_, B_), 128, 0, stream>>>(Xb, w1swz, efo1, PT1, counts + 0);

  fused_layer2<<<dim3(NCHUNK_, B_), 128, 0, stream>>>(PT1, wswz, efo2, PT2, counts + 1);

  gemm3_kernel<<<dim3(T_ / 256, B_), 256, 0, stream>>>(PT2, w3T, z3);
  scan3_kernel<<<dim3(NCHUNK_ * B_ * NOUT_ / 64), 64, 0, stream>>>(z3, out, counts + 2);
}